// Round 1
// baseline (61.465 us; speedup 1.0000x reference)
//
#include <hip/hip_runtime.h>
#include <stdint.h>

#define T_DIM 64
#define IN_DIM 4096
#define OUT_DIM 8192
#define NGROUPS 16
#define GS 256                       // group size along K
#define SPLITK 4
#define KCHUNK (IN_DIM / SPLITK)     // 1024
#define GROUPS_PER_CHUNK (KCHUNK / GS)  // 4

typedef __attribute__((ext_vector_type(4))) float f32x4;
typedef __attribute__((ext_vector_type(8))) __bf16 bf16x8;

__device__ __forceinline__ unsigned short f2bf(float f) {
    union { float f; unsigned int u; } v; v.f = f;
    unsigned int u = v.u;
    // round-to-nearest-even bf16
    return (unsigned short)((u + 0x7FFFu + ((u >> 16) & 1u)) >> 16);
}

__global__ void zero_kernel(float4* __restrict__ p, int n4) {
    int i = blockIdx.x * blockDim.x + threadIdx.x;
    if (i < n4) p[i] = make_float4(0.f, 0.f, 0.f, 0.f);
}

__global__ void cvt_kernel(const float* __restrict__ x, unsigned short* __restrict__ xb, int n) {
    int i = (blockIdx.x * blockDim.x + threadIdx.x) * 4;
    if (i < n) {
        float4 f = *(const float4*)(x + i);
        ushort4 o;
        o.x = f2bf(f.x); o.y = f2bf(f.y); o.z = f2bf(f.z); o.w = f2bf(f.w);
        *(ushort4*)(xb + i) = o;
    }
}

// Each wave: 64(M) x 16(N) output strip over one K-chunk of 1024.
// Block = 4 waves = 64 consecutive output columns. grid = (8192/64, SPLITK).
template<bool PRE>
__global__ __launch_bounds__(256, 2)
void qgemm(const float* __restrict__ x, const unsigned short* __restrict__ xb,
           const int* __restrict__ qw, const float* __restrict__ qrange,
           const float* __restrict__ qmin, float* __restrict__ out)
{
    const int lane = threadIdx.x & 63;
    const int wv   = threadIdx.x >> 6;
    const int r    = lane & 15;      // fragment row/col index
    const int q4   = lane >> 4;      // 0..3 quad
    const int obase = blockIdx.x * 64 + wv * 16;
    const int o    = obase + r;      // this lane's output column (B operand col)
    const int ks   = blockIdx.y;
    const int kbase = ks * KCHUNK;

    const int* __restrict__ qrow = qw + (size_t)o * IN_DIM + kbase + q4 * 8;
    const unsigned short* __restrict__ xrow = xb + (size_t)r * IN_DIM + kbase + q4 * 8;
    const float* __restrict__ xrowf = x + (size_t)r * IN_DIM + kbase + q4 * 8;

    f32x4 acc[4] = {{0,0,0,0},{0,0,0,0},{0,0,0,0},{0,0,0,0}};

    #pragma unroll
    for (int g = 0; g < GROUPS_PER_CHUNK; ++g) {
        const int gg = ks * GROUPS_PER_CHUNK + g;
        const float scale = qrange[o * NGROUPS + gg];
        const float mn    = qmin[o * NGROUPS + gg];
        #pragma unroll
        for (int it = 0; it < GS / 32; ++it) {
            const int k0 = g * GS + it * 32;   // offset within this K-chunk
            // ---- B fragment: 8 consecutive int32 codes of row o, dequant -> bf16
            int4 c0 = *(const int4*)(qrow + k0);
            int4 c1 = *(const int4*)(qrow + k0 + 4);
            bf16x8 b;
            unsigned short* bu = (unsigned short*)&b;
            bu[0] = f2bf((float)c0.x * scale + mn);
            bu[1] = f2bf((float)c0.y * scale + mn);
            bu[2] = f2bf((float)c0.z * scale + mn);
            bu[3] = f2bf((float)c0.w * scale + mn);
            bu[4] = f2bf((float)c1.x * scale + mn);
            bu[5] = f2bf((float)c1.y * scale + mn);
            bu[6] = f2bf((float)c1.z * scale + mn);
            bu[7] = f2bf((float)c1.w * scale + mn);
            // ---- A fragments: 4 M-tiles (rows m*16 + r), 8 bf16 each
            bf16x8 a[4];
            #pragma unroll
            for (int m = 0; m < 4; ++m) {
                if (PRE) {
                    a[m] = *(const bf16x8*)(xrow + (size_t)(m * 16) * IN_DIM + k0);
                } else {
                    const float* xp = xrowf + (size_t)(m * 16) * IN_DIM + k0;
                    float4 f0 = *(const float4*)xp;
                    float4 f1 = *(const float4*)(xp + 4);
                    unsigned short* au = (unsigned short*)&a[m];
                    au[0] = f2bf(f0.x); au[1] = f2bf(f0.y);
                    au[2] = f2bf(f0.z); au[3] = f2bf(f0.w);
                    au[4] = f2bf(f1.x); au[5] = f2bf(f1.y);
                    au[6] = f2bf(f1.z); au[7] = f2bf(f1.w);
                }
            }
            acc[0] = __builtin_amdgcn_mfma_f32_16x16x32_bf16(a[0], b, acc[0], 0, 0, 0);
            acc[1] = __builtin_amdgcn_mfma_f32_16x16x32_bf16(a[1], b, acc[1], 0, 0, 0);
            acc[2] = __builtin_amdgcn_mfma_f32_16x16x32_bf16(a[2], b, acc[2], 0, 0, 0);
            acc[3] = __builtin_amdgcn_mfma_f32_16x16x32_bf16(a[3], b, acc[3], 0, 0, 0);
        }
    }

    // D layout: col = lane&15 (= o), row = (lane>>4)*4 + j, per m-tile of 16
    #pragma unroll
    for (int m = 0; m < 4; ++m) {
        #pragma unroll
        for (int j = 0; j < 4; ++j) {
            const int t = m * 16 + q4 * 4 + j;
            unsafeAtomicAdd(&out[(size_t)t * OUT_DIM + o], acc[m][j]);
        }
    }
}

extern "C" void kernel_launch(void* const* d_in, const int* in_sizes, int n_in,
                              void* d_out, int out_size, void* d_ws, size_t ws_size,
                              hipStream_t stream)
{
    const float* x      = (const float*)d_in[0];
    const int*   qw     = (const int*)d_in[1];
    const float* qrange = (const float*)d_in[2];
    const float* qmin   = (const float*)d_in[3];
    float* out = (float*)d_out;

    // zero output (split-K accumulates with atomics; harness poisons d_out)
    const int n4 = out_size / 4;
    zero_kernel<<<dim3((n4 + 255) / 256), dim3(256), 0, stream>>>((float4*)d_out, n4);

    const int nx = T_DIM * IN_DIM;                  // 262144
    const size_t xb_bytes = (size_t)nx * sizeof(unsigned short);
    if (ws_size >= xb_bytes) {
        unsigned short* xb = (unsigned short*)d_ws;
        cvt_kernel<<<dim3(nx / 4 / 256), dim3(256), 0, stream>>>(x, xb, nx);
        qgemm<true><<<dim3(OUT_DIM / 64, SPLITK), dim3(256), 0, stream>>>(x, xb, qw, qrange, qmin, out);
    } else {
        qgemm<false><<<dim3(OUT_DIM / 64, SPLITK), dim3(256), 0, stream>>>(x, nullptr, qw, qrange, qmin, out);
    }
}